// Round 11
// baseline (6204.822 us; speedup 1.0000x reference)
//
#include <hip/hip_runtime.h>

#define S_LEN 512
#define BATCH 128
#define NH    128
#define NL    3

#define HXS  392   // hx row stride (shorts)
#define INPS 136   // inp row stride (shorts)

// workspace layout (bytes)
#define XP_OFF   0u
#define WP_OFF   16777216u              // 384 frags * 1KB
#define UP_OFF   (WP_OFF + 393216u)     // 1152 frags * 1KB
#define HX_OFF   (UP_OFF + 1179648u)    // 2par*8grp*3l*16row*24chunk*16B = 294912
#define HX_SZ    294912u

typedef float f32x4 __attribute__((ext_vector_type(4)));
typedef short bf16x8 __attribute__((ext_vector_type(8)));
typedef unsigned u32x4 __attribute__((ext_vector_type(4)));
typedef unsigned long long u64;

__device__ __forceinline__ short f2bf(float f) {
    unsigned u = __builtin_bit_cast(unsigned, f);
    u = (u + 0x7FFFu + ((u >> 16) & 1u)) >> 16;
    return (short)u;
}
__device__ __forceinline__ float bf2f_lo(unsigned u) { return __builtin_bit_cast(float, u << 16); }
__device__ __forceinline__ float bf2f_hi(unsigned u) { return __builtin_bit_cast(float, u & 0xFFFF0000u); }
__device__ __forceinline__ float sigm(float x) { return 1.f / (1.f + __expf(-x)); }
__device__ __forceinline__ float tanh_fast(float x) { return 2.f / (1.f + __expf(-2.f * x)) - 1.f; }

// ---------------- K1: xp = x @ lin_w.T + lin_b  ->  bf16 [S*B][H] ----------------
__global__ __launch_bounds__(128) void xp_kernel(const float* __restrict__ x,
        const float* __restrict__ lin_w, const float* __restrict__ lin_b,
        short* __restrict__ xp) {
    __shared__ float xs[8 * 128];
    const int tid = threadIdx.x;
    const long r0 = (long)blockIdx.x * 8;
    for (int rr = 0; rr < 8; ++rr)
        xs[rr * 128 + tid] = x[(r0 + rr) * 128 + tid];
    __syncthreads();
    float acc[8];
    float bias = lin_b[tid];
    #pragma unroll
    for (int rr = 0; rr < 8; ++rr) acc[rr] = bias;
    const float* wrow = lin_w + (long)tid * 128;
    for (int k = 0; k < 128; ++k) {
        float wv = wrow[k];
        #pragma unroll
        for (int rr = 0; rr < 8; ++rr) acc[rr] += xs[rr * 128 + k] * wv;
    }
    for (int rr = 0; rr < 8; ++rr)
        xp[(r0 + rr) * 128 + tid] = f2bf(acc[rr]);
}

// ---------------- K2: pack W,U per (unit, gate-wave) fragment-linear ----------------
__global__ __launch_bounds__(256) void pack_kernel(const float* __restrict__ W,
        const float* __restrict__ U, short* __restrict__ Wp, short* __restrict__ Up) {
    int id = blockIdx.x * 256 + threadIdx.x;     // 98304 = 1536 frags * 64 lanes
    int lane = id & 63;
    int fid = id >> 6;
    int lr = lane & 15, lk = lane >> 4;
    if (fid < 384) {
        int kt = fid & 3, g = (fid >> 2) & 3, unit = fid >> 4;
        int l = unit >> 3, c = unit & 7;
        int row = g * 128 + c * 16 + lr;
        const float* src = W + ((long)(l * 512 + row)) * 128 + kt * 32 + lk * 8;
        short* dst = Wp + (long)fid * 512 + lane * 8;
        #pragma unroll
        for (int j = 0; j < 8; ++j) dst[j] = f2bf(src[j]);
    } else {
        int f = fid - 384;
        int kt = f % 12, gu = f / 12;
        int g = gu & 3, unit = gu >> 2;
        int l = unit >> 3, c = unit & 7;
        int row = g * 128 + c * 16 + lr;
        const float* src = U + ((long)(l * 512 + row)) * 384 + kt * 32 + lk * 8;
        short* dst = Up + (long)f * 512 + lane * 8;
        #pragma unroll
        for (int j = 0; j < 8; ++j) dst[j] = f2bf(src[j]);
    }
}

// chunk geometry: per (slot,grp,l) block = 16 rows x 24 chunks x 16B.
// chunk m = c*3 + j: shorts [6j..6j+valid) of publisher c's 16 cols; 16B=[d0][d1][d2][tag], tag=t+1.

#define POLL6(q0,q1,q2,q3,q4,q5,ab) \
    asm volatile( \
        "global_load_dwordx4 %0, %6, off sc0 sc1\n\t" \
        "global_load_dwordx4 %1, %6, off offset:16 sc0 sc1\n\t" \
        "global_load_dwordx4 %2, %6, off offset:32 sc0 sc1\n\t" \
        "global_load_dwordx4 %3, %6, off offset:48 sc0 sc1\n\t" \
        "global_load_dwordx4 %4, %6, off offset:64 sc0 sc1\n\t" \
        "global_load_dwordx4 %5, %6, off offset:80 sc0 sc1\n\t" \
        "s_waitcnt vmcnt(0)" \
        : "=&v"(q0), "=&v"(q1), "=&v"(q2), "=&v"(q3), "=&v"(q4), "=&v"(q5) \
        : "v"(ab) : "memory")

// ---------------- main: 192 WGs (24 units x 8 batch groups), rotated schedule ----------------
__global__ __launch_bounds__(256, 1) void lstm_kernel(
    const short* __restrict__ xp, const short* __restrict__ Wp,
    const short* __restrict__ Up, const float* __restrict__ Gp,
    char* __restrict__ hexch, float* __restrict__ out)
{
    __shared__ short hx_lds[16 * HXS];        // 12544 B
    __shared__ short inp_lds[16 * INPS];      //  4352 B
    __shared__ float gates_lds[4 * 16 * 17];  //  4352 B
    __shared__ float G_lds[NL * 128];         //  1536 B

    const int tid  = threadIdx.x;
    const int lane = tid & 63;
    const int w    = tid >> 6;        // wave 0..3 = gate index (i,f,g,o)
    const int lr   = lane & 15;
    const int lk   = lane >> 4;
    const int grp  = blockIdx.x & 7;
    const int unit = blockIdx.x >> 3;
    const int l    = unit >> 3;
    const int c    = unit & 7;
    const int b0   = grp * 16;

    // ---- weights resident in VGPRs, pinned ----
    bf16x8 ufr[12], wfr[4];
    {
        const short* ub = Up + ((long)(unit * 4 + w) * 12) * 512 + lane * 8;
        #pragma unroll
        for (int kt = 0; kt < 12; ++kt) ufr[kt] = *(const bf16x8*)(ub + kt * 512);
        const short* wb = Wp + ((long)(unit * 4 + w) * 4) * 512 + lane * 8;
        #pragma unroll
        for (int kt = 0; kt < 4; ++kt) wfr[kt] = *(const bf16x8*)(wb + kt * 512);
    }
    #pragma unroll
    for (int kt = 0; kt < 12; ++kt) asm volatile("" : "+v"(ufr[kt]));
    #pragma unroll
    for (int kt = 0; kt < 4; ++kt)  asm volatile("" : "+v"(wfr[kt]));

    for (int i = tid; i < NL * 128; i += 256) G_lds[i] = Gp[i];
    for (int i = tid; i < 16 * HXS; i += 256) hx_lds[i] = 0;   // h(-1) = 0
    float c6[6] = {0.f, 0.f, 0.f, 0.f, 0.f, 0.f};              // cell state (wave3 lanes<48)
    const int crow = lane / 3, cjj = lane % 3;                  // cell/publish mapping
    __syncthreads();

    const int offs[6] = {0, 6, 12, 16, 22, 28};
    const int nw[6]   = {3, 3, 2, 3, 3, 2};

    f32x4 acc0 = (f32x4){0.f, 0.f, 0.f, 0.f};   // carries kt0..7 partials from prefetch
    f32x4 acc1 = (f32x4){0.f, 0.f, 0.f, 0.f};

    for (int t = 0; t < S_LEN; ++t) {
        const int par = t & 1;

        bf16x8 xa[4];
        if (l == 0) {
            const short* xp_t = xp + ((long)t * BATCH + b0) * 128;
            #pragma unroll
            for (int kt = 0; kt < 4; ++kt)
                xa[kt] = *(const bf16x8*)(xp_t + lr * 128 + kt * 32 + lk * 8);
        }

        // ===== critical poll: wave2 fetches h(t-1, 2), builds hx l2-slice =====
        if (t > 0 && w == 2) {
            const int p = lane >> 2, sub = lane & 3;
            const unsigned want = (unsigned)t;
            const u64 abase = (u64)(hexch + (size_t)((((par ^ 1) * 8 + grp) * 3 + 2)) * 6144
                                          + ((size_t)p * 24 + sub * 6) * 16);
            u32x4 q0, q1, q2, q3, q4, q5;
            for (int rounds = 0;; ++rounds) {
                POLL6(q0, q1, q2, q3, q4, q5, abase);
                bool fresh = (q0[3] == want) && (q1[3] == want) && (q2[3] == want)
                          && (q3[3] == want) && (q4[3] == want) && (q5[3] == want);
                if (__all(fresh) || rounds > 262144) break;
            }
            const float* gb = &G_lds[2 * 128 + sub * 32];
            float s = 0.f;
            u32x4 qs[6] = {q0, q1, q2, q3, q4, q5};
            #pragma unroll
            for (int k = 0; k < 6; ++k)
                #pragma unroll
                for (int i = 0; i < 3; ++i)
                    if (i < nw[k]) {
                        unsigned wd = qs[k][i];
                        s += bf2f_lo(wd) * gb[offs[k] + 2 * i]
                           + bf2f_hi(wd) * gb[offs[k] + 2 * i + 1];
                    }
            s += __shfl_xor(s, 1, 64);
            s += __shfl_xor(s, 2, 64);
            float gh = sigm(s);
            #pragma unroll
            for (int k = 0; k < 6; ++k)
                #pragma unroll
                for (int i = 0; i < 3; ++i)
                    if (i < nw[k]) {
                        unsigned wd = qs[k][i];
                        unsigned r = (unsigned)(unsigned short)f2bf(gh * bf2f_lo(wd))
                                   | ((unsigned)(unsigned short)f2bf(gh * bf2f_hi(wd)) << 16);
                        *(unsigned*)&hx_lds[p * HXS + 2 * 128 + sub * 32 + offs[k] + 2 * i] = r;
                    }
        }
        __syncthreads();   // b_hx2

        // ===== U GEMM tail: kt 8..11 (l2 slice) =====
        #pragma unroll
        for (int kt = 8; kt < 12; ++kt) {
            bf16x8 a = *(const bf16x8*)&hx_lds[lr * HXS + kt * 32 + lk * 8];
            if (kt & 1) acc1 = __builtin_amdgcn_mfma_f32_16x16x32_bf16(a, ufr[kt], acc1, 0, 0, 0);
            else        acc0 = __builtin_amdgcn_mfma_f32_16x16x32_bf16(a, ufr[kt], acc0, 0, 0, 0);
        }

        // ===== W phase =====
        if (l == 0) {
            #pragma unroll
            for (int kt = 0; kt < 4; ++kt) {
                if (kt & 1) acc1 = __builtin_amdgcn_mfma_f32_16x16x32_bf16(xa[kt], wfr[kt], acc1, 0, 0, 0);
                else        acc0 = __builtin_amdgcn_mfma_f32_16x16x32_bf16(xa[kt], wfr[kt], acc0, 0, 0, 0);
            }
        } else {
            const unsigned want = (unsigned)(t + 1);
            const u64 base = (u64)(hexch + (size_t)(((par * 8 + grp) * 3 + (l - 1))) * 6144);
            const u64 a0 = base + (size_t)tid * 16;
            const u64 a1 = a0 + 4096;
            u32x4 q0, q1;
            if (tid < 128) {
                for (int rounds = 0;; ++rounds) {
                    asm volatile(
                        "global_load_dwordx4 %0, %2, off sc0 sc1\n\t"
                        "global_load_dwordx4 %1, %3, off sc0 sc1\n\t"
                        "s_waitcnt vmcnt(0)"
                        : "=&v"(q0), "=&v"(q1) : "v"(a0), "v"(a1) : "memory");
                    if (__all((q0[3] == want) && (q1[3] == want)) || rounds > 262144) break;
                }
            } else {
                for (int rounds = 0;; ++rounds) {
                    asm volatile(
                        "global_load_dwordx4 %0, %1, off sc0 sc1\n\t"
                        "s_waitcnt vmcnt(0)"
                        : "=&v"(q0) : "v"(a0) : "memory");
                    if (__all(q0[3] == want) || rounds > 262144) break;
                }
            }
            {
                int row = tid / 24, m = tid % 24, cc = m / 3, j = m % 3;
                int sbase = row * INPS + cc * 16 + 6 * j;
                *(unsigned*)&inp_lds[sbase] = q0[0];
                *(unsigned*)&inp_lds[sbase + 2] = q0[1];
                if (j < 2) *(unsigned*)&inp_lds[sbase + 4] = q0[2];
                if (tid < 128) {
                    int ch1 = tid + 256;
                    int row1 = ch1 / 24, m1 = ch1 % 24, c1 = m1 / 3, j1 = m1 % 3;
                    int sb1 = row1 * INPS + c1 * 16 + 6 * j1;
                    *(unsigned*)&inp_lds[sb1] = q1[0];
                    *(unsigned*)&inp_lds[sb1 + 2] = q1[1];
                    if (j1 < 2) *(unsigned*)&inp_lds[sb1 + 4] = q1[2];
                }
            }
            __syncthreads();   // b_inp
            #pragma unroll
            for (int kt = 0; kt < 4; ++kt) {
                bf16x8 a = *(const bf16x8*)&inp_lds[lr * INPS + kt * 32 + lk * 8];
                if (kt & 1) acc1 = __builtin_amdgcn_mfma_f32_16x16x32_bf16(a, wfr[kt], acc1, 0, 0, 0);
                else        acc0 = __builtin_amdgcn_mfma_f32_16x16x32_bf16(a, wfr[kt], acc0, 0, 0, 0);
            }
        }

        // ===== gates to LDS, reset accumulators for next step =====
        #pragma unroll
        for (int r = 0; r < 4; ++r)
            gates_lds[w * 272 + (lk * 4 + r) * 17 + lr] = acc0[r] + acc1[r];
        acc0 = (f32x4){0.f, 0.f, 0.f, 0.f};
        acc1 = (f32x4){0.f, 0.f, 0.f, 0.f};
        __syncthreads();   // b_gates

        // ===== fused cell + pack + publish (wave3 lanes 0..47) =====
        if (w == 3 && lane < 48) {
            const int nv = (cjj == 2) ? 4 : 6;
            unsigned dw0 = 0, dw1 = 0, dw2 = 0;
            #pragma unroll
            for (int k = 0; k < 6; ++k) {
                if (k < nv) {
                    int col = cjj * 6 + k;
                    float ig = sigm(gates_lds[0 * 272 + crow * 17 + col]);
                    float fg = sigm(gates_lds[1 * 272 + crow * 17 + col]);
                    float gg = tanh_fast(gates_lds[2 * 272 + crow * 17 + col]);
                    float og = sigm(gates_lds[3 * 272 + crow * 17 + col]);
                    float cn = fg * c6[k] + ig * gg;
                    c6[k] = cn;
                    float hy = og * tanh_fast(cn);
                    unsigned hb = (unsigned)(unsigned short)f2bf(hy) << ((k & 1) * 16);
                    if (k < 2)      dw0 |= hb;
                    else if (k < 4) dw1 |= hb;
                    else            dw2 |= hb;
                    if (t == S_LEN - 1) {
                        long o = ((long)(l * BATCH + b0 + crow)) * NH + c * 16 + col;
                        out[o] = hy;
                        out[(long)NL * BATCH * NH + o] = cn;
                    }
                }
            }
            u32x4 dq = (u32x4){dw0, dw1, dw2, (unsigned)(t + 1)};
            u64 pa = (u64)(hexch + (size_t)(((par * 8 + grp) * 3 + l)) * 6144
                                 + ((size_t)crow * 24 + c * 3 + cjj) * 16);
            asm volatile("global_store_dwordx4 %0, %1, off sc0 sc1" :: "v"(pa), "v"(dq) : "memory");
        }

        // ===== prefetch for step t+1: layers 0,1 of h(t) + kt0..7 MFMAs =====
        if (t < S_LEN - 1) {
            if (w < 2) {
                const int p = lane >> 2, sub = lane & 3;
                const unsigned want = (unsigned)(t + 1);
                const u64 abase = (u64)(hexch + (size_t)(((par * 8 + grp) * 3 + w)) * 6144
                                              + ((size_t)p * 24 + sub * 6) * 16);
                u32x4 q0, q1, q2, q3, q4, q5;
                for (int rounds = 0;; ++rounds) {
                    POLL6(q0, q1, q2, q3, q4, q5, abase);
                    bool fresh = (q0[3] == want) && (q1[3] == want) && (q2[3] == want)
                              && (q3[3] == want) && (q4[3] == want) && (q5[3] == want);
                    if (__all(fresh) || rounds > 262144) break;
                }
                const float* gb = &G_lds[w * 128 + sub * 32];
                float s = 0.f;
                u32x4 qs[6] = {q0, q1, q2, q3, q4, q5};
                #pragma unroll
                for (int k = 0; k < 6; ++k)
                    #pragma unroll
                    for (int i = 0; i < 3; ++i)
                        if (i < nw[k]) {
                            unsigned wd = qs[k][i];
                            s += bf2f_lo(wd) * gb[offs[k] + 2 * i]
                               + bf2f_hi(wd) * gb[offs[k] + 2 * i + 1];
                        }
                s += __shfl_xor(s, 1, 64);
                s += __shfl_xor(s, 2, 64);
                float gh = sigm(s);
                #pragma unroll
                for (int k = 0; k < 6; ++k)
                    #pragma unroll
                    for (int i = 0; i < 3; ++i)
                        if (i < nw[k]) {
                            unsigned wd = qs[k][i];
                            unsigned r = (unsigned)(unsigned short)f2bf(gh * bf2f_lo(wd))
                                       | ((unsigned)(unsigned short)f2bf(gh * bf2f_hi(wd)) << 16);
                            *(unsigned*)&hx_lds[p * HXS + w * 128 + sub * 32 + offs[k] + 2 * i] = r;
                        }
            }
            __syncthreads();   // b_hx01
            #pragma unroll
            for (int kt = 0; kt < 8; ++kt) {
                bf16x8 a = *(const bf16x8*)&hx_lds[lr * HXS + kt * 32 + lk * 8];
                if (kt & 1) acc1 = __builtin_amdgcn_mfma_f32_16x16x32_bf16(a, ufr[kt], acc1, 0, 0, 0);
                else        acc0 = __builtin_amdgcn_mfma_f32_16x16x32_bf16(a, ufr[kt], acc0, 0, 0, 0);
            }
        }
    }
}

extern "C" void kernel_launch(void* const* d_in, const int* in_sizes, int n_in,
                              void* d_out, int out_size, void* d_ws, size_t ws_size,
                              hipStream_t stream) {
    const float* x     = (const float*)d_in[0];
    const float* lin_w = (const float*)d_in[1];
    const float* lin_b = (const float*)d_in[2];
    const float* W     = (const float*)d_in[3];
    const float* U     = (const float*)d_in[4];
    const float* G     = (const float*)d_in[5];
    float* out = (float*)d_out;

    short* xp    = (short*)((char*)d_ws + XP_OFF);
    short* Wp    = (short*)((char*)d_ws + WP_OFF);
    short* Up    = (short*)((char*)d_ws + UP_OFF);
    char*  hexch = (char*)d_ws + HX_OFF;

    hipMemsetAsync(hexch, 0, HX_SZ, stream);   // clear tags every launch (replay-safe)
    hipLaunchKernelGGL(xp_kernel,   dim3(8192), dim3(128), 0, stream, x, lin_w, lin_b, xp);
    hipLaunchKernelGGL(pack_kernel, dim3(384),  dim3(256), 0, stream, W, U, Wp, Up);
    hipLaunchKernelGGL(lstm_kernel, dim3(192),  dim3(256), 0, stream,
                       xp, Wp, Up, G, hexch, out);
}

// Round 13
// 3291.933 us; speedup vs baseline: 1.8849x; 1.8849x over previous
//
#include <hip/hip_runtime.h>

#define S_LEN 512
#define BATCH 128
#define NH    128
#define NL    3

#define HXS  392   // hx row stride (shorts)
#define INPS 136   // inp row stride (shorts)

// workspace layout (bytes)
#define XP_OFF   0u
#define WP_OFF   16777216u              // 384 frags * 1KB
#define UP_OFF   (WP_OFF + 393216u)     // 1152 frags * 1KB
#define HX_OFF   (UP_OFF + 1179648u)    // 2par*8grp*3l * 128col*4rg * 16B = 393216
#define HX_SZ    393216u

typedef float f32x4 __attribute__((ext_vector_type(4)));
typedef short bf16x8 __attribute__((ext_vector_type(8)));
typedef unsigned u32x4 __attribute__((ext_vector_type(4)));
typedef unsigned long long u64;

__device__ __forceinline__ short f2bf(float f) {
    unsigned u = __builtin_bit_cast(unsigned, f);
    u = (u + 0x7FFFu + ((u >> 16) & 1u)) >> 16;
    return (short)u;
}
__device__ __forceinline__ float bf2f_lo(unsigned u) { return __builtin_bit_cast(float, u << 16); }
__device__ __forceinline__ float bf2f_hi(unsigned u) { return __builtin_bit_cast(float, u & 0xFFFF0000u); }
// short r (0..3) of a chunk payload {q[0],q[1]} -> float
__device__ __forceinline__ float chf(const u32x4& q, int r) {
    unsigned wd = (r < 2) ? q[0] : q[1];
    return (r & 1) ? bf2f_hi(wd) : bf2f_lo(wd);
}
__device__ __forceinline__ float sigm(float x) { return 1.f / (1.f + __expf(-x)); }
__device__ __forceinline__ float tanh_fast(float x) { return 2.f / (1.f + __expf(-2.f * x)) - 1.f; }

// ---------------- K1: xp = x @ lin_w.T + lin_b  ->  bf16 [S*B][H] ----------------
__global__ __launch_bounds__(128) void xp_kernel(const float* __restrict__ x,
        const float* __restrict__ lin_w, const float* __restrict__ lin_b,
        short* __restrict__ xp) {
    __shared__ float xs[8 * 128];
    const int tid = threadIdx.x;
    const long r0 = (long)blockIdx.x * 8;
    for (int rr = 0; rr < 8; ++rr)
        xs[rr * 128 + tid] = x[(r0 + rr) * 128 + tid];
    __syncthreads();
    float acc[8];
    float bias = lin_b[tid];
    #pragma unroll
    for (int rr = 0; rr < 8; ++rr) acc[rr] = bias;
    const float* wrow = lin_w + (long)tid * 128;
    for (int k = 0; k < 128; ++k) {
        float wv = wrow[k];
        #pragma unroll
        for (int rr = 0; rr < 8; ++rr) acc[rr] += xs[rr * 128 + k] * wv;
    }
    for (int rr = 0; rr < 8; ++rr)
        xp[(r0 + rr) * 128 + tid] = f2bf(acc[rr]);
}

// ---------------- K2: pack W,U; B-frag rows = gate-remap ----------------
// Wave w of unit (l,c) owns n-tile rows: row(n) = (n>>2)*128 + c*16 + w*4 + (n&3), n=lane&15.
// k = kt*32 + (lane>>4)*8 + j.
// Wp frag id = (unit*4+w)*4 + kt  [384];  Up frag id = (unit*4+w)*12 + kt  [1152]
__global__ __launch_bounds__(256) void pack_kernel(const float* __restrict__ W,
        const float* __restrict__ U, short* __restrict__ Wp, short* __restrict__ Up) {
    int id = blockIdx.x * 256 + threadIdx.x;     // 98304 = 1536 frags * 64 lanes
    int lane = id & 63;
    int fid = id >> 6;
    int n = lane & 15, lk = lane >> 4;
    if (fid < 384) {
        int kt = fid & 3, w = (fid >> 2) & 3, unit = fid >> 4;
        int l = unit >> 3, c = unit & 7;
        int row = (n >> 2) * 128 + c * 16 + w * 4 + (n & 3);
        const float* src = W + ((long)(l * 512 + row)) * 128 + kt * 32 + lk * 8;
        short* dst = Wp + (long)fid * 512 + lane * 8;
        #pragma unroll
        for (int j = 0; j < 8; ++j) dst[j] = f2bf(src[j]);
    } else {
        int f = fid - 384;
        int kt = f % 12, gu = f / 12;
        int w = gu & 3, unit = gu >> 2;
        int l = unit >> 3, c = unit & 7;
        int row = (n >> 2) * 128 + c * 16 + w * 4 + (n & 3);
        const float* src = U + ((long)(l * 512 + row)) * 384 + kt * 32 + lk * 8;
        short* dst = Up + (long)f * 512 + lane * 8;
        #pragma unroll
        for (int j = 0; j < 8; ++j) dst[j] = f2bf(src[j]);
    }
}

// chunk geometry: per (slot,grp,l) block = 128 cols x 4 rowgroups x 16B, addr = (col*4+rg)*16.
// payload: d0 = h[rg*4+0]|h[rg*4+1]<<16, d1 = h[rg*4+2]|h[rg*4+3]<<16, word2 = 0, word3 = tag = t+1.

// ---------------- main: 192 WGs (24 units x 8 groups), concurrent polls, in-reg cell ----------------
__global__ __launch_bounds__(256, 1) void lstm_kernel(
    const short* __restrict__ xp, const short* __restrict__ Wp,
    const short* __restrict__ Up, const float* __restrict__ Gp,
    char* __restrict__ hexch, float* __restrict__ out)
{
    __shared__ short hx_lds[16 * HXS];        // 12544 B
    __shared__ short inp_lds[16 * INPS];      //  4352 B
    __shared__ float G_lds[NL * 128];         //  1536 B
    __shared__ unsigned hxflag;               // layer-2 hx ready tag

    const int tid  = threadIdx.x;
    const int lane = tid & 63;
    const int w    = tid >> 6;        // wave 0..3
    const int lr   = lane & 15;       // A-row / B-n index
    const int lk   = lane >> 4;       // k-chunk / batch row-group
    const int grp  = blockIdx.x & 7;
    const int unit = blockIdx.x >> 3;
    const int l    = unit >> 3;
    const int c    = unit & 7;
    const int b0   = grp * 16;

    // ---- weights resident in VGPRs, pinned ----
    bf16x8 ufr[12], wfr[4];
    {
        const short* ub = Up + ((long)(unit * 4 + w) * 12) * 512 + lane * 8;
        #pragma unroll
        for (int kt = 0; kt < 12; ++kt) ufr[kt] = *(const bf16x8*)(ub + kt * 512);
        const short* wb = Wp + ((long)(unit * 4 + w) * 4) * 512 + lane * 8;
        #pragma unroll
        for (int kt = 0; kt < 4; ++kt) wfr[kt] = *(const bf16x8*)(wb + kt * 512);
    }
    #pragma unroll
    for (int kt = 0; kt < 12; ++kt) asm volatile("" : "+v"(ufr[kt]));
    #pragma unroll
    for (int kt = 0; kt < 4; ++kt)  asm volatile("" : "+v"(wfr[kt]));

    for (int i = tid; i < NL * 128; i += 256) G_lds[i] = Gp[i];
    for (int i = tid; i < 16 * HXS; i += 256) hx_lds[i] = 0;   // h(-1) = 0
    if (tid == 0) hxflag = 0;
    float c_reg[4] = {0.f, 0.f, 0.f, 0.f};     // cell state (lanes with lr<4)
    __syncthreads();

    for (int t = 0; t < S_LEN; ++t) {
        const int par = t & 1;
        __syncthreads();   // b_top: step t-1 fully consumed LDS

        bf16x8 xa[4];
        if (l == 0) {
            const short* xp_t = xp + ((long)t * BATCH + b0) * 128;
            #pragma unroll
            for (int kt = 0; kt < 4; ++kt)
                xa[kt] = *(const bf16x8*)(xp_t + lr * 128 + kt * 32 + lk * 8);
        }

        // ===== U-read: waves 0,1 -> layers 0,1 (long-visible; built before b1) =====
        const int rg = lane >> 4, cg = lane & 15;   // reader mapping
        if (t > 0 && w < 2) {
            const unsigned want = (unsigned)t;
            const u64 ab = (u64)(hexch + (size_t)((((par ^ 1) * 8 + grp) * 3 + w)) * 8192
                                       + (size_t)cg * 512 + (size_t)rg * 16);
            u32x4 q0, q1, q2, q3, q4, q5, q6, q7;
            for (int rounds = 0;; ++rounds) {
                asm volatile(
                    "global_load_dwordx4 %0, %8, off sc0 sc1\n\t"
                    "global_load_dwordx4 %1, %8, off offset:64 sc0 sc1\n\t"
                    "global_load_dwordx4 %2, %8, off offset:128 sc0 sc1\n\t"
                    "global_load_dwordx4 %3, %8, off offset:192 sc0 sc1\n\t"
                    "global_load_dwordx4 %4, %8, off offset:256 sc0 sc1\n\t"
                    "global_load_dwordx4 %5, %8, off offset:320 sc0 sc1\n\t"
                    "global_load_dwordx4 %6, %8, off offset:384 sc0 sc1\n\t"
                    "global_load_dwordx4 %7, %8, off offset:448 sc0 sc1\n\t"
                    "s_waitcnt vmcnt(0)"
                    : "=&v"(q0), "=&v"(q1), "=&v"(q2), "=&v"(q3),
                      "=&v"(q4), "=&v"(q5), "=&v"(q6), "=&v"(q7)
                    : "v"(ab) : "memory");
                bool fr = (q0[3] == want) && (q1[3] == want) && (q2[3] == want) && (q3[3] == want)
                       && (q4[3] == want) && (q5[3] == want) && (q6[3] == want) && (q7[3] == want);
                if (__all(fr) || rounds > 262144) break;
            }
            u32x4 qs[8] = {q0, q1, q2, q3, q4, q5, q6, q7};
            const float* gb = &G_lds[w * 128 + cg * 8];
            float s[4] = {0.f, 0.f, 0.f, 0.f};
            #pragma unroll
            for (int k = 0; k < 8; ++k) {
                float gk = gb[k];
                #pragma unroll
                for (int r = 0; r < 4; ++r) s[r] += chf(qs[k], r) * gk;
            }
            #pragma unroll
            for (int m = 1; m <= 8; m <<= 1)
                #pragma unroll
                for (int r = 0; r < 4; ++r) s[r] += __shfl_xor(s[r], m, 64);
            #pragma unroll
            for (int r = 0; r < 4; ++r) {
                float gh = sigm(s[r]);
                unsigned wd[4];
                #pragma unroll
                for (int jj = 0; jj < 4; ++jj)
                    wd[jj] = (unsigned)(unsigned short)f2bf(gh * chf(qs[2 * jj], r))
                           | ((unsigned)(unsigned short)f2bf(gh * chf(qs[2 * jj + 1], r)) << 16);
                *(u32x4*)&hx_lds[(rg * 4 + r) * HXS + w * 128 + cg * 8] =
                    (u32x4){wd[0], wd[1], wd[2], wd[3]};
            }
        }
        __syncthreads();   // b1: hx01 ready; wave3 joins BEFORE its long poll

        // ===== wave3: poll layer 2 of h(t-1), build hx2, release LDS flag =====
        if (t > 0 && w == 3) {
            const unsigned want = (unsigned)t;
            const u64 ab = (u64)(hexch + (size_t)((((par ^ 1) * 8 + grp) * 3 + 2)) * 8192
                                       + (size_t)cg * 512 + (size_t)rg * 16);
            u32x4 q0, q1, q2, q3, q4, q5, q6, q7;
            for (int rounds = 0;; ++rounds) {
                asm volatile(
                    "global_load_dwordx4 %0, %8, off sc0 sc1\n\t"
                    "global_load_dwordx4 %1, %8, off offset:64 sc0 sc1\n\t"
                    "global_load_dwordx4 %2, %8, off offset:128 sc0 sc1\n\t"
                    "global_load_dwordx4 %3, %8, off offset:192 sc0 sc1\n\t"
                    "global_load_dwordx4 %4, %8, off offset:256 sc0 sc1\n\t"
                    "global_load_dwordx4 %5, %8, off offset:320 sc0 sc1\n\t"
                    "global_load_dwordx4 %6, %8, off offset:384 sc0 sc1\n\t"
                    "global_load_dwordx4 %7, %8, off offset:448 sc0 sc1\n\t"
                    "s_waitcnt vmcnt(0)"
                    : "=&v"(q0), "=&v"(q1), "=&v"(q2), "=&v"(q3),
                      "=&v"(q4), "=&v"(q5), "=&v"(q6), "=&v"(q7)
                    : "v"(ab) : "memory");
                bool fr = (q0[3] == want) && (q1[3] == want) && (q2[3] == want) && (q3[3] == want)
                       && (q4[3] == want) && (q5[3] == want) && (q6[3] == want) && (q7[3] == want);
                if (__all(fr) || rounds > 262144) break;
            }
            u32x4 qs[8] = {q0, q1, q2, q3, q4, q5, q6, q7};
            const float* gb = &G_lds[2 * 128 + cg * 8];
            float s[4] = {0.f, 0.f, 0.f, 0.f};
            #pragma unroll
            for (int k = 0; k < 8; ++k) {
                float gk = gb[k];
                #pragma unroll
                for (int r = 0; r < 4; ++r) s[r] += chf(qs[k], r) * gk;
            }
            #pragma unroll
            for (int m = 1; m <= 8; m <<= 1)
                #pragma unroll
                for (int r = 0; r < 4; ++r) s[r] += __shfl_xor(s[r], m, 64);
            #pragma unroll
            for (int r = 0; r < 4; ++r) {
                float gh = sigm(s[r]);
                unsigned wd[4];
                #pragma unroll
                for (int jj = 0; jj < 4; ++jj)
                    wd[jj] = (unsigned)(unsigned short)f2bf(gh * chf(qs[2 * jj], r))
                           | ((unsigned)(unsigned short)f2bf(gh * chf(qs[2 * jj + 1], r)) << 16);
                *(u32x4*)&hx_lds[(rg * 4 + r) * HXS + 2 * 128 + cg * 8] =
                    (u32x4){wd[0], wd[1], wd[2], wd[3]};
            }
            if (lane == 0)
                __hip_atomic_store(&hxflag, (unsigned)t, __ATOMIC_RELEASE, __HIP_MEMORY_SCOPE_WORKGROUP);
        }

        // ===== U GEMM: kt0..7 during wave3's poll; kt8..11 after LDS flag =====
        f32x4 acc0 = (f32x4){0.f, 0.f, 0.f, 0.f};
        f32x4 acc1 = (f32x4){0.f, 0.f, 0.f, 0.f};
        #pragma unroll
        for (int kt = 0; kt < 8; ++kt) {
            bf16x8 a = *(const bf16x8*)&hx_lds[lr * HXS + kt * 32 + lk * 8];
            if (kt & 1) acc1 = __builtin_amdgcn_mfma_f32_16x16x32_bf16(a, ufr[kt], acc1, 0, 0, 0);
            else        acc0 = __builtin_amdgcn_mfma_f32_16x16x32_bf16(a, ufr[kt], acc0, 0, 0, 0);
        }
        if (t > 0) {
            int guard = 0;
            while (__hip_atomic_load(&hxflag, __ATOMIC_ACQUIRE, __HIP_MEMORY_SCOPE_WORKGROUP)
                   < (unsigned)t) {
                if (++guard > 40000000) break;
            }
        }
        #pragma unroll
        for (int kt = 8; kt < 12; ++kt) {
            bf16x8 a = *(const bf16x8*)&hx_lds[lr * HXS + kt * 32 + lk * 8];
            if (kt & 1) acc1 = __builtin_amdgcn_mfma_f32_16x16x32_bf16(a, ufr[kt], acc1, 0, 0, 0);
            else        acc0 = __builtin_amdgcn_mfma_f32_16x16x32_bf16(a, ufr[kt], acc0, 0, 0, 0);
        }

        // ===== W phase =====
        if (l == 0) {
            #pragma unroll
            for (int kt = 0; kt < 4; ++kt) {
                if (kt & 1) acc1 = __builtin_amdgcn_mfma_f32_16x16x32_bf16(xa[kt], wfr[kt], acc1, 0, 0, 0);
                else        acc0 = __builtin_amdgcn_mfma_f32_16x16x32_bf16(xa[kt], wfr[kt], acc0, 0, 0, 0);
            }
        } else {
            const unsigned want = (unsigned)(t + 1);
            const u64 base = (u64)(hexch + (size_t)(((par * 8 + grp) * 3 + (l - 1))) * 8192);
            const u64 a0 = base + (size_t)tid * 16;
            const u64 a1 = a0 + 4096;            // separate addr reg: imm offset caps at 4095
            u32x4 q0, q1;
            for (int rounds = 0;; ++rounds) {
                asm volatile(
                    "global_load_dwordx4 %0, %2, off sc0 sc1\n\t"
                    "global_load_dwordx4 %1, %3, off sc0 sc1\n\t"
                    "s_waitcnt vmcnt(0)"
                    : "=&v"(q0), "=&v"(q1) : "v"(a0), "v"(a1) : "memory");
                if (__all((q0[3] == want) && (q1[3] == want)) || rounds > 262144) break;
            }
            {
                int col0 = tid >> 2, rg0 = tid & 3;
                inp_lds[(rg0 * 4 + 0) * INPS + col0] = (short)(q0[0] & 0xffff);
                inp_lds[(rg0 * 4 + 1) * INPS + col0] = (short)(q0[0] >> 16);
                inp_lds[(rg0 * 4 + 2) * INPS + col0] = (short)(q0[1] & 0xffff);
                inp_lds[(rg0 * 4 + 3) * INPS + col0] = (short)(q0[1] >> 16);
                int m1 = tid + 256, col1 = m1 >> 2, rg1 = m1 & 3;
                inp_lds[(rg1 * 4 + 0) * INPS + col1] = (short)(q1[0] & 0xffff);
                inp_lds[(rg1 * 4 + 1) * INPS + col1] = (short)(q1[0] >> 16);
                inp_lds[(rg1 * 4 + 2) * INPS + col1] = (short)(q1[1] & 0xffff);
                inp_lds[(rg1 * 4 + 3) * INPS + col1] = (short)(q1[1] >> 16);
            }
            __syncthreads();   // b_inp
            #pragma unroll
            for (int kt = 0; kt < 4; ++kt) {
                bf16x8 a = *(const bf16x8*)&inp_lds[lr * INPS + kt * 32 + lk * 8];
                if (kt & 1) acc1 = __builtin_amdgcn_mfma_f32_16x16x32_bf16(a, wfr[kt], acc1, 0, 0, 0);
                else        acc0 = __builtin_amdgcn_mfma_f32_16x16x32_bf16(a, wfr[kt], acc0, 0, 0, 0);
            }
        }

        // ===== in-register cell: shfl gates across n (4=f, 8=g, 12=o), lanes lr<4 compute =====
        f32x4 ac = acc0 + acc1;
        f32x4 vf, vg, vo;
        #pragma unroll
        for (int r = 0; r < 4; ++r) {
            vf[r] = __shfl_xor(ac[r], 4, 64);
            vg[r] = __shfl_xor(ac[r], 8, 64);
            vo[r] = __shfl_xor(ac[r], 12, 64);
        }
        if (lr < 4) {
            unsigned hw[2];
            float hys[4], cns[4];
            #pragma unroll
            for (int r = 0; r < 4; ++r) {
                float ig = sigm(ac[r]);
                float fg = sigm(vf[r]);
                float gg = tanh_fast(vg[r]);
                float og = sigm(vo[r]);
                float cn = fg * c_reg[r] + ig * gg;
                c_reg[r] = cn;
                cns[r] = cn;
                hys[r] = og * tanh_fast(cn);
            }
            hw[0] = (unsigned)(unsigned short)f2bf(hys[0])
                  | ((unsigned)(unsigned short)f2bf(hys[1]) << 16);
            hw[1] = (unsigned)(unsigned short)f2bf(hys[2])
                  | ((unsigned)(unsigned short)f2bf(hys[3]) << 16);
            u32x4 dq = (u32x4){hw[0], hw[1], 0u, (unsigned)(t + 1)};
            const int col = c * 16 + w * 4 + lr;
            u64 pa = (u64)(hexch + (size_t)(((par * 8 + grp) * 3 + l)) * 8192
                                 + ((size_t)col * 4 + lk) * 16);
            asm volatile("global_store_dwordx4 %0, %1, off sc0 sc1" :: "v"(pa), "v"(dq) : "memory");
            if (t == S_LEN - 1) {
                #pragma unroll
                for (int r = 0; r < 4; ++r) {
                    long o = ((long)(l * BATCH + b0 + lk * 4 + r)) * NH + col;
                    out[o] = hys[r];
                    out[(long)NL * BATCH * NH + o] = cns[r];
                }
            }
        }
    }
}

extern "C" void kernel_launch(void* const* d_in, const int* in_sizes, int n_in,
                              void* d_out, int out_size, void* d_ws, size_t ws_size,
                              hipStream_t stream) {
    const float* x     = (const float*)d_in[0];
    const float* lin_w = (const float*)d_in[1];
    const float* lin_b = (const float*)d_in[2];
    const float* W     = (const float*)d_in[3];
    const float* U     = (const float*)d_in[4];
    const float* G     = (const float*)d_in[5];
    float* out = (float*)d_out;

    short* xp    = (short*)((char*)d_ws + XP_OFF);
    short* Wp    = (short*)((char*)d_ws + WP_OFF);
    short* Up    = (short*)((char*)d_ws + UP_OFF);
    char*  hexch = (char*)d_ws + HX_OFF;

    (void)hipMemsetAsync(hexch, 0, HX_SZ, stream);   // clear tags every launch (replay-safe)
    hipLaunchKernelGGL(xp_kernel,   dim3(8192), dim3(128), 0, stream, x, lin_w, lin_b, xp);
    hipLaunchKernelGGL(pack_kernel, dim3(384),  dim3(256), 0, stream, W, U, Wp, Up);
    hipLaunchKernelGGL(lstm_kernel, dim3(192),  dim3(256), 0, stream,
                       xp, Wp, Up, G, hexch, out);
}